// Round 7
// baseline (1569.885 us; speedup 1.0000x reference)
//
#include <hip/hip_runtime.h>
#include <hip/hip_bf16.h>
#include <cstdint>
#include <cstddef>

// ---------------------------------------------------------------------------
// GCN encoder, bf16-MFMA version. CSR build via 2-pass stable LSD radix sort
// by dst (8-bit digits). R7: histogram TRANSPOSED to h[digit][block] so the
// single-block scan walks contiguous per-thread rows (was: strided lockstep
// round-trips), and NB=1024 (was 256) to cut scatter serial depth 98->25.
// Stable sort => csr sorted by (dst, edge id) => bit-identical fp32 sums on
// every call (harness re-validates after graph replay).
// GEMMs: LDS-free MFMA 16x16x32 bf16; same bijective k-assignment on both
// operands (symmetric A/B maps) => exact regardless of HW k layout.
// ---------------------------------------------------------------------------

using frag_ab = __attribute__((ext_vector_type(8))) short;  // 8 bf16
using f32x4   = __attribute__((ext_vector_type(4))) float;
typedef unsigned short u16;

#define NB 1024  // radix partition blocks (contiguous edge ranges)

__device__ __forceinline__ short f2bf(float f) {
    return __builtin_bit_cast(short, __float2bfloat16(f));
}

// ------------------------------- degrees -----------------------------------

__global__ __launch_bounds__(256) void count_kernel(const int* __restrict__ dst, int E,
                                                    int* __restrict__ counts) {
    int i = blockIdx.x * blockDim.x + threadIdx.x;
    int stride = gridDim.x * blockDim.x;
    for (; i < E; i += stride) atomicAdd(&counts[dst[i]], 1);
}

__global__ __launch_bounds__(256) void dinv_kernel(const int* __restrict__ counts,
                                                   float* __restrict__ dinv, int n) {
    int i = blockIdx.x * blockDim.x + threadIdx.x;
    if (i < n) dinv[i] = rsqrtf((float)(counts[i] + 1));  // +1 self-loop
}

// Single-block scan: counts -> exclusive offsets.
__global__ __launch_bounds__(1024) void scan_kernel(const int* __restrict__ counts,
                                                    int* __restrict__ offs,
                                                    int n, int total) {
    __shared__ int ssum[1024];
    const int tid = threadIdx.x;
    const int chunk = (n + 1023) / 1024;
    const int beg = tid * chunk;
    const int end = min(beg + chunk, n);
    int local = 0;
    for (int i = beg; i < end; ++i) local += counts[i];
    ssum[tid] = local;
    __syncthreads();
    for (int off = 1; off < 1024; off <<= 1) {
        int v = (tid >= off) ? ssum[tid - off] : 0;
        __syncthreads();
        ssum[tid] += v;
        __syncthreads();
    }
    int run = ssum[tid] - local;
    for (int i = beg; i < end; ++i) {
        offs[i] = run;
        run += counts[i];
    }
    if (tid == 0) offs[n] = total;
}

// --------------------------- radix sort by dst -----------------------------
// PASS 1: digit = dst & 255, input = (dst[], src[]), output = uint2(dst,src).
// PASS 2: digit = dst >> 8,  input = uint2 recs,     output = csr[] (src only).
// Histogram layout: h[digit * NB + block]  (TRANSPOSED: rows per digit).

template<int PASS>
__global__ __launch_bounds__(256) void hist_kernel(const void* __restrict__ in,
                                                   int E, int CH,
                                                   int* __restrict__ h) {
    __shared__ int hist[256];
    const int b = blockIdx.x;
    const int t = threadIdx.x;
    hist[t] = 0;
    __syncthreads();
    const int beg = b * CH;
    const int end = min(beg + CH, E);
    if constexpr (PASS == 1) {
        const int* dst = (const int*)in;
        for (int i = beg + t; i < end; i += 256) atomicAdd(&hist[dst[i] & 255], 1);
    } else {
        const uint2* rec = (const uint2*)in;
        for (int i = beg + t; i < end; i += 256) atomicAdd(&hist[(int)(rec[i].x >> 8)], 1);
    }
    __syncthreads();
    h[t * NB + b] = hist[t];  // transposed store
}

// Transposed scan: thread d owns contiguous row h[d][0..nb) -> sequential
// per-thread walk (lines fetched once, loads pipeline), then cross-digit
// exclusive scan in LDS, then vectorized add-back.
__global__ __launch_bounds__(256) void scan_hist(int* __restrict__ h, int nb) {
    __shared__ int tot[256];
    const int d = threadIdx.x;
    int* row = h + (size_t)d * nb;
    int run = 0;
    for (int b = 0; b < nb; ++b) {
        int v = row[b];
        row[b] = run;
        run += v;
    }
    tot[d] = run;
    __syncthreads();
    for (int o = 1; o < 256; o <<= 1) {
        int u = (d >= o) ? tot[d - o] : 0;
        __syncthreads();
        tot[d] += u;
        __syncthreads();
    }
    const int digbase = tot[d] - run;  // exclusive prefix across digits
    for (int b = 0; b < nb; ++b) row[b] += digbase;
}

// Stable scatter: ONE wave per block walks its contiguous range in order.
// Per 64-edge batch: 8-ballot bit-serial equality mask -> per-digit rank;
// per-digit cursors in LDS (init from scanned histogram); last-ranked lane
// advances the cursor. Output regions per (block,digit) are contiguous.
template<int PASS>
__global__ __launch_bounds__(64) void scatter_kernel(const void* __restrict__ in,
                                                     const int* __restrict__ srcv,
                                                     int E, int CH,
                                                     const int* __restrict__ base,
                                                     void* __restrict__ outv) {
    __shared__ int cur[256];
    const int b = blockIdx.x;
    const int lane = threadIdx.x;
    for (int t = lane; t < 256; t += 64) cur[t] = base[t * NB + b];  // transposed read
    const int beg = b * CH;
    const int end = min(beg + CH, E);
    const unsigned long long below = (1ull << lane) - 1;
    for (int i0 = beg; i0 < end; i0 += 64) {
        const int i = i0 + lane;
        const bool act = i < end;
        int d = 0, s = 0;
        if (act) {
            if constexpr (PASS == 1) {
                d = ((const int*)in)[i];
                s = srcv[i];
            } else {
                uint2 r = ((const uint2*)in)[i];
                d = (int)r.x;
                s = (int)r.y;
            }
        }
        const int dig = (PASS == 1) ? (d & 255) : (d >> 8);
        unsigned long long m = __ballot(act);
#pragma unroll
        for (int bit = 0; bit < 8; ++bit) {
            unsigned long long bb = __ballot((dig >> bit) & 1);
            m &= ((dig >> bit) & 1) ? bb : ~bb;
        }
        if (act) {
            const int rank = __popcll(m & below);
            const int cnt = __popcll(m);
            const int c = cur[dig];  // LDS broadcast: same for all same-dig lanes
            if (rank == cnt - 1) cur[dig] = c + cnt;  // last lane advances cursor
            if constexpr (PASS == 1)
                ((uint2*)outv)[c + rank] = make_uint2((unsigned)d, (unsigned)s);
            else
                ((int*)outv)[c + rank] = s;
        }
    }
}

// --------------------------- weight prep (bf16^T) --------------------------

__global__ __launch_bounds__(256) void prep_w(const float* __restrict__ W,
                                              short* __restrict__ Wt, int K, int N) {
    int i = blockIdx.x * 256 + threadIdx.x;  // over K*N
    if (i >= K * N) return;
    int k = i / N, nn = i - k * N;
    Wt[(size_t)nn * K + k] = f2bf(W[i]);
}

// ------------------------------- MFMA GEMM ---------------------------------
// C[M,N] = A[M,K] @ Bt[N,K]^T. 256 threads = 4 waves (WM x WN); wave does
// 64 x (NI*16). No LDS/barriers; fragments direct from global.
template<int WM, int WN, int NI, bool A_BF16, bool SCALE, bool BIAS, bool OUT_BF16>
__global__ __launch_bounds__(256) void gemm_mfma(const void* __restrict__ Av,
                                                 const short* __restrict__ Bt,
                                                 const float* __restrict__ dinv,
                                                 const float* __restrict__ bias,
                                                 void* __restrict__ Cv,
                                                 int M, int N, int K) {
    constexpr int TM = WM * 64;
    constexpr int TN = WN * NI * 16;
    const int wid = threadIdx.x >> 6;
    const int lane = threadIdx.x & 63;
    const int wm = wid / WN;
    const int wn = wid % WN;
    const int bm = blockIdx.y * TM + wm * 64;
    const int bn = blockIdx.x * TN + wn * NI * 16;
    const int r15 = lane & 15;
    const int g = lane >> 4;

    f32x4 acc[4][NI] = {};

    int arow[4];
#pragma unroll
    for (int mi = 0; mi < 4; ++mi) arow[mi] = min(bm + mi * 16 + r15, M - 1);

    for (int k0 = 0; k0 < K; k0 += 32) {
        const int kb = k0 + g * 8;
        frag_ab af[4];
#pragma unroll
        for (int mi = 0; mi < 4; ++mi) {
            if constexpr (A_BF16) {
                af[mi] = *(const frag_ab*)((const short*)Av + (size_t)arow[mi] * K + kb);
            } else {
                const float* ap = (const float*)Av + (size_t)arow[mi] * K + kb;
                float4 lo = *(const float4*)ap;
                float4 hi = *(const float4*)(ap + 4);
                frag_ab t;
                t[0] = f2bf(lo.x); t[1] = f2bf(lo.y); t[2] = f2bf(lo.z); t[3] = f2bf(lo.w);
                t[4] = f2bf(hi.x); t[5] = f2bf(hi.y); t[6] = f2bf(hi.z); t[7] = f2bf(hi.w);
                af[mi] = t;
            }
        }
        frag_ab bf[NI];
#pragma unroll
        for (int ni = 0; ni < NI; ++ni)
            bf[ni] = *(const frag_ab*)(Bt + (size_t)(bn + ni * 16 + r15) * K + kb);
#pragma unroll
        for (int mi = 0; mi < 4; ++mi)
#pragma unroll
            for (int ni = 0; ni < NI; ++ni)
                acc[mi][ni] = __builtin_amdgcn_mfma_f32_16x16x32_bf16(af[mi], bf[ni],
                                                                      acc[mi][ni], 0, 0, 0);
    }

#pragma unroll
    for (int mi = 0; mi < 4; ++mi) {
#pragma unroll
        for (int j = 0; j < 4; ++j) {
            const int row = bm + mi * 16 + g * 4 + j;
            if (row >= M) continue;
            const float s = SCALE ? dinv[row] : 1.0f;
#pragma unroll
            for (int ni = 0; ni < NI; ++ni) {
                const int col = bn + ni * 16 + r15;
                float v = acc[mi][ni][j] * s;
                if (BIAS) v += bias[col];
                if constexpr (OUT_BF16)
                    ((short*)Cv)[(size_t)row * N + col] = f2bf(v);
                else
                    ((float*)Cv)[(size_t)row * N + col] = v;
            }
        }
    }
}

// ------------------------------ aggregation --------------------------------
// out[d] = relu(dinv[d]*(sum_{s in CSR[d]} hs[s] + hs[d]) + b). bf16 in/out,
// fp32 accum, self term last. One wave per node, V bf16 per lane.
template<int V>
__device__ __forceinline__ void vloadbf(float (&d)[V], const u16* __restrict__ p) {
    if constexpr (V == 4) {
        uint2 u = *(const uint2*)p;
        d[0] = __builtin_bit_cast(float, u.x << 16);
        d[1] = __builtin_bit_cast(float, u.x & 0xffff0000u);
        d[2] = __builtin_bit_cast(float, u.y << 16);
        d[3] = __builtin_bit_cast(float, u.y & 0xffff0000u);
    } else {
        unsigned u = *(const unsigned*)p;
        d[0] = __builtin_bit_cast(float, u << 16);
        d[1] = __builtin_bit_cast(float, u & 0xffff0000u);
    }
}

template<int V>
__global__ __launch_bounds__(256) void agg_kernel(const u16* __restrict__ hs,
                                                  const int* __restrict__ csr,
                                                  const int* __restrict__ offs,
                                                  const float* __restrict__ dinv,
                                                  const float* __restrict__ bias,
                                                  u16* __restrict__ out,
                                                  int n, int F) {
    const int node = blockIdx.x * 4 + (threadIdx.x >> 6);
    if (node >= n) return;
    const int lane = threadIdx.x & 63;
    const int c0 = lane * V;

    float self[V];
    vloadbf<V>(self, hs + (size_t)node * F + c0);

    float acc[V];
#pragma unroll
    for (int j = 0; j < V; ++j) acc[j] = 0.f;

    int e = offs[node];
    const int end = offs[node + 1];
    for (; e + 4 <= end; e += 4) {
        int s0 = csr[e], s1 = csr[e + 1], s2 = csr[e + 2], s3 = csr[e + 3];
        float t0[V], t1[V], t2[V], t3[V];
        vloadbf<V>(t0, hs + (size_t)s0 * F + c0);
        vloadbf<V>(t1, hs + (size_t)s1 * F + c0);
        vloadbf<V>(t2, hs + (size_t)s2 * F + c0);
        vloadbf<V>(t3, hs + (size_t)s3 * F + c0);
#pragma unroll
        for (int j = 0; j < V; ++j) acc[j] += ((t0[j] + t1[j]) + (t2[j] + t3[j]));
    }
    for (; e < end; ++e) {
        float tv[V];
        vloadbf<V>(tv, hs + (size_t)csr[e] * F + c0);
#pragma unroll
        for (int j = 0; j < V; ++j) acc[j] += tv[j];
    }

    const float di = dinv[node];
    u16 res[V];
#pragma unroll
    for (int j = 0; j < V; ++j) {
        float v = fmaf(acc[j] + self[j], di, bias[c0 + j]);
        res[j] = (u16)f2bf(fmaxf(v, 0.f));
    }
    if constexpr (V == 4) {
        uint2 o;
        o.x = (unsigned)res[0] | ((unsigned)res[1] << 16);
        o.y = (unsigned)res[2] | ((unsigned)res[3] << 16);
        *(uint2*)(out + (size_t)node * F + c0) = o;
    } else {
        unsigned o = (unsigned)res[0] | ((unsigned)res[1] << 16);
        *(unsigned*)(out + (size_t)node * F + c0) = o;
    }
}

// ---------------------------------------------------------------------------

extern "C" void kernel_launch(void* const* d_in, const int* in_sizes, int n_in,
                              void* d_out, int out_size, void* d_ws, size_t ws_size,
                              hipStream_t stream) {
    const float* x  = (const float*)d_in[0];
    const int*   ei = (const int*)d_in[1];
    const float* W1 = (const float*)d_in[2];
    const float* b1 = (const float*)d_in[3];
    const float* W2 = (const float*)d_in[4];
    const float* b2 = (const float*)d_in[5];
    const float* Wl = (const float*)d_in[6];
    const float* bl = (const float*)d_in[7];

    const int E = in_sizes[1] / 2;    // 1,600,000
    const int n = in_sizes[0] / 256;  // 50,000
    const int* src = ei;
    const int* dst = ei + E;
    const int CH = (E + NB - 1) / NB;

    char* ws = (char*)d_ws;
    size_t off = 0;
    auto alloc = [&](size_t bytes) -> void* {
        void* p = ws + off;
        off += (bytes + 255) & ~(size_t)255;
        return p;
    };
    short* h      = (short*)alloc((size_t)n * 256 * 2);   // bf16 h1 / h2
    short* a      = (short*)alloc((size_t)n * 256 * 2);   // bf16 a1 / a2
    int*   counts = (int*)alloc((size_t)n * 4);
    int*   offs   = (int*)alloc((size_t)(n + 1) * 4);
    float* dinv   = (float*)alloc((size_t)n * 4);
    int*   csr    = (int*)alloc((size_t)E * 4);
    int*   h1     = (int*)alloc((size_t)NB * 256 * 4);
    int*   h2     = (int*)alloc((size_t)NB * 256 * 4);
    short* wt1    = (short*)alloc((size_t)256 * 256 * 2);
    short* wt2    = (short*)alloc((size_t)128 * 256 * 2);
    short* wtl    = (short*)alloc((size_t)64 * 128 * 2);
    // rec1 (12.8 MB) aliases 'a' (25.6 MB): CSR build completes before 'a' is used.
    uint2* rec1   = (uint2*)a;
    (void)ws_size;

    hipMemsetAsync(counts, 0, (size_t)n * 4, stream);
    prep_w<<<(256 * 256 + 255) / 256, 256, 0, stream>>>(W1, wt1, 256, 256);
    prep_w<<<(256 * 128 + 255) / 256, 256, 0, stream>>>(W2, wt2, 256, 128);
    prep_w<<<(128 * 64 + 255) / 256, 256, 0, stream>>>(Wl, wtl, 128, 64);

    count_kernel<<<1024, 256, 0, stream>>>(dst, E, counts);
    dinv_kernel<<<(n + 255) / 256, 256, 0, stream>>>(counts, dinv, n);
    scan_kernel<<<1, 1024, 0, stream>>>(counts, offs, n, E);

    // Stable radix sort by dst: pass 1 (low byte) then pass 2 (high byte).
    hist_kernel<1><<<NB, 256, 0, stream>>>(dst, E, CH, h1);
    scan_hist<<<1, 256, 0, stream>>>(h1, NB);
    scatter_kernel<1><<<NB, 64, 0, stream>>>(dst, src, E, CH, h1, rec1);
    hist_kernel<2><<<NB, 256, 0, stream>>>(rec1, E, CH, h2);
    scan_hist<<<1, 256, 0, stream>>>(h2, NB);
    scatter_kernel<2><<<NB, 64, 0, stream>>>(rec1, nullptr, E, CH, h2, csr);

    // Layer 1: h = (x @ W1) * dinv[row]  [bf16]; a = relu(agg(h) + b1) [bf16]
    gemm_mfma<2, 2, 4, false, true, false, true>
        <<<dim3(2, (n + 127) / 128), 256, 0, stream>>>(x, wt1, dinv, nullptr, h, n, 256, 256);
    agg_kernel<4><<<(n + 3) / 4, 256, 0, stream>>>((const u16*)h, csr, offs, dinv, b1,
                                                   (u16*)a, n, 256);

    // Layer 2: h = (a @ W2) * dinv[row] [bf16]; a = relu(agg(h) + b2) [bf16]
    gemm_mfma<1, 4, 2, true, true, false, true>
        <<<dim3(1, (n + 63) / 64), 256, 0, stream>>>(a, wt2, dinv, nullptr, h, n, 128, 256);
    agg_kernel<2><<<(n + 3) / 4, 256, 0, stream>>>((const u16*)h, csr, offs, dinv, b2,
                                                   (u16*)a, n, 128);

    // Head: out = a @ Wl + bl  [fp32]
    gemm_mfma<1, 4, 1, true, false, true, false>
        <<<dim3(1, (n + 63) / 64), 256, 0, stream>>>(a, wtl, nullptr, bl, d_out, n, 64, 128);
}

// Round 8
// 571.770 us; speedup vs baseline: 2.7457x; 2.7457x over previous
//
#include <hip/hip_runtime.h>
#include <hip/hip_bf16.h>
#include <cstdint>
#include <cstddef>

// ---------------------------------------------------------------------------
// GCN encoder, bf16-MFMA version. CSR build via 2-pass stable LSD radix sort
// by dst (8-bit digits), histogram h[digit][block]. R8: the histogram scan is
// now a parallel 3-stage hierarchy (row_scan: 1 block/digit; digit_scan: 256
// totals; digit base folded into scatter cursor init) -- replaces the serial
// single-block scan_hist that cost 2x509us in R7.
// Stable sort => csr sorted by (dst, edge id) => bit-identical fp32 sums on
// every call (harness re-validates after graph replay).
// GEMMs: LDS-free MFMA 16x16x32 bf16; same bijective k-assignment on both
// operands (symmetric A/B maps) => exact regardless of HW k layout.
// ---------------------------------------------------------------------------

using frag_ab = __attribute__((ext_vector_type(8))) short;  // 8 bf16
using f32x4   = __attribute__((ext_vector_type(4))) float;
typedef unsigned short u16;

#define NB 1024  // radix partition blocks (contiguous edge ranges)

__device__ __forceinline__ short f2bf(float f) {
    return __builtin_bit_cast(short, __float2bfloat16(f));
}

// ------------------------------- degrees -----------------------------------

__global__ __launch_bounds__(256) void count_kernel(const int* __restrict__ dst, int E,
                                                    int* __restrict__ counts) {
    int i = blockIdx.x * blockDim.x + threadIdx.x;
    int stride = gridDim.x * blockDim.x;
    for (; i < E; i += stride) atomicAdd(&counts[dst[i]], 1);
}

__global__ __launch_bounds__(256) void dinv_kernel(const int* __restrict__ counts,
                                                   float* __restrict__ dinv, int n) {
    int i = blockIdx.x * blockDim.x + threadIdx.x;
    if (i < n) dinv[i] = rsqrtf((float)(counts[i] + 1));  // +1 self-loop
}

// Single-block scan: counts -> exclusive offsets (n=50000: 49 elems/thread).
__global__ __launch_bounds__(1024) void scan_kernel(const int* __restrict__ counts,
                                                    int* __restrict__ offs,
                                                    int n, int total) {
    __shared__ int ssum[1024];
    const int tid = threadIdx.x;
    const int chunk = (n + 1023) / 1024;
    const int beg = tid * chunk;
    const int end = min(beg + chunk, n);
    int local = 0;
    for (int i = beg; i < end; ++i) local += counts[i];
    ssum[tid] = local;
    __syncthreads();
    for (int off = 1; off < 1024; off <<= 1) {
        int v = (tid >= off) ? ssum[tid - off] : 0;
        __syncthreads();
        ssum[tid] += v;
        __syncthreads();
    }
    int run = ssum[tid] - local;
    for (int i = beg; i < end; ++i) {
        offs[i] = run;
        run += counts[i];
    }
    if (tid == 0) offs[n] = total;
}

// --------------------------- radix sort by dst -----------------------------
// PASS 1: digit = dst & 255, input = (dst[], src[]), output = uint2(dst,src).
// PASS 2: digit = dst >> 8,  input = uint2 recs,     output = csr[] (src only).
// Histogram layout: h[digit * NB + block].

template<int PASS>
__global__ __launch_bounds__(256) void hist_kernel(const void* __restrict__ in,
                                                   int E, int CH,
                                                   int* __restrict__ h) {
    __shared__ int hist[256];
    const int b = blockIdx.x;
    const int t = threadIdx.x;
    hist[t] = 0;
    __syncthreads();
    const int beg = b * CH;
    const int end = min(beg + CH, E);
    if constexpr (PASS == 1) {
        const int* dst = (const int*)in;
        for (int i = beg + t; i < end; i += 256) atomicAdd(&hist[dst[i] & 255], 1);
    } else {
        const uint2* rec = (const uint2*)in;
        for (int i = beg + t; i < end; i += 256) atomicAdd(&hist[(int)(rec[i].x >> 8)], 1);
    }
    __syncthreads();
    h[t * NB + b] = hist[t];  // transposed store
}

// Stage 1: block d scans its row h[d][0..NB) in parallel (int4/thread + LDS
// block scan), leaves exclusive within-row prefixes, writes row total.
__global__ __launch_bounds__(256) void row_scan_kernel(int* __restrict__ h,
                                                       int* __restrict__ tot) {
    __shared__ int part[256];
    const int d = blockIdx.x;
    const int t = threadIdx.x;
    int* row = h + (size_t)d * NB;
    int4 v = *(int4*)(row + t * 4);
    const int s = v.x + v.y + v.z + v.w;
    part[t] = s;
    __syncthreads();
    for (int o = 1; o < 256; o <<= 1) {
        int u = (t >= o) ? part[t - o] : 0;
        __syncthreads();
        part[t] += u;
        __syncthreads();
    }
    const int ex = part[t] - s;
    int4 o4;
    o4.x = ex;
    o4.y = ex + v.x;
    o4.z = ex + v.x + v.y;
    o4.w = ex + v.x + v.y + v.z;
    *(int4*)(row + t * 4) = o4;
    if (t == 255) tot[d] = part[255];
}

// Stage 2: exclusive scan of 256 digit totals -> digbase.
__global__ __launch_bounds__(256) void digit_scan_kernel(const int* __restrict__ tot,
                                                         int* __restrict__ digbase) {
    __shared__ int s[256];
    const int t = threadIdx.x;
    const int v = tot[t];
    s[t] = v;
    __syncthreads();
    for (int o = 1; o < 256; o <<= 1) {
        int u = (t >= o) ? s[t - o] : 0;
        __syncthreads();
        s[t] += u;
        __syncthreads();
    }
    digbase[t] = s[t] - v;
}

// Stable scatter: ONE wave per block walks its contiguous range in order.
// Per 64-edge batch: 8-ballot bit-serial equality mask -> per-digit rank;
// per-digit cursors in LDS (init = within-digit base + digit base); the
// last-ranked lane advances the cursor.
template<int PASS>
__global__ __launch_bounds__(64) void scatter_kernel(const void* __restrict__ in,
                                                     const int* __restrict__ srcv,
                                                     int E, int CH,
                                                     const int* __restrict__ base,
                                                     const int* __restrict__ digbase,
                                                     void* __restrict__ outv) {
    __shared__ int cur[256];
    const int b = blockIdx.x;
    const int lane = threadIdx.x;
    for (int t = lane; t < 256; t += 64) cur[t] = base[t * NB + b] + digbase[t];
    const int beg = b * CH;
    const int end = min(beg + CH, E);
    const unsigned long long below = (1ull << lane) - 1;
    for (int i0 = beg; i0 < end; i0 += 64) {
        const int i = i0 + lane;
        const bool act = i < end;
        int d = 0, s = 0;
        if (act) {
            if constexpr (PASS == 1) {
                d = ((const int*)in)[i];
                s = srcv[i];
            } else {
                uint2 r = ((const uint2*)in)[i];
                d = (int)r.x;
                s = (int)r.y;
            }
        }
        const int dig = (PASS == 1) ? (d & 255) : (d >> 8);
        unsigned long long m = __ballot(act);
#pragma unroll
        for (int bit = 0; bit < 8; ++bit) {
            unsigned long long bb = __ballot((dig >> bit) & 1);
            m &= ((dig >> bit) & 1) ? bb : ~bb;
        }
        if (act) {
            const int rank = __popcll(m & below);
            const int cnt = __popcll(m);
            const int c = cur[dig];  // LDS broadcast: same for all same-dig lanes
            if (rank == cnt - 1) cur[dig] = c + cnt;  // last lane advances cursor
            if constexpr (PASS == 1)
                ((uint2*)outv)[c + rank] = make_uint2((unsigned)d, (unsigned)s);
            else
                ((int*)outv)[c + rank] = s;
        }
    }
}

// --------------------------- weight prep (bf16^T) --------------------------

__global__ __launch_bounds__(256) void prep_w(const float* __restrict__ W,
                                              short* __restrict__ Wt, int K, int N) {
    int i = blockIdx.x * 256 + threadIdx.x;  // over K*N
    if (i >= K * N) return;
    int k = i / N, nn = i - k * N;
    Wt[(size_t)nn * K + k] = f2bf(W[i]);
}

// ------------------------------- MFMA GEMM ---------------------------------
// C[M,N] = A[M,K] @ Bt[N,K]^T. 256 threads = 4 waves (WM x WN); wave does
// 64 x (NI*16). No LDS/barriers; fragments direct from global.
template<int WM, int WN, int NI, bool A_BF16, bool SCALE, bool BIAS, bool OUT_BF16>
__global__ __launch_bounds__(256) void gemm_mfma(const void* __restrict__ Av,
                                                 const short* __restrict__ Bt,
                                                 const float* __restrict__ dinv,
                                                 const float* __restrict__ bias,
                                                 void* __restrict__ Cv,
                                                 int M, int N, int K) {
    constexpr int TM = WM * 64;
    constexpr int TN = WN * NI * 16;
    const int wid = threadIdx.x >> 6;
    const int lane = threadIdx.x & 63;
    const int wm = wid / WN;
    const int wn = wid % WN;
    const int bm = blockIdx.y * TM + wm * 64;
    const int bn = blockIdx.x * TN + wn * NI * 16;
    const int r15 = lane & 15;
    const int g = lane >> 4;

    f32x4 acc[4][NI] = {};

    int arow[4];
#pragma unroll
    for (int mi = 0; mi < 4; ++mi) arow[mi] = min(bm + mi * 16 + r15, M - 1);

    for (int k0 = 0; k0 < K; k0 += 32) {
        const int kb = k0 + g * 8;
        frag_ab af[4];
#pragma unroll
        for (int mi = 0; mi < 4; ++mi) {
            if constexpr (A_BF16) {
                af[mi] = *(const frag_ab*)((const short*)Av + (size_t)arow[mi] * K + kb);
            } else {
                const float* ap = (const float*)Av + (size_t)arow[mi] * K + kb;
                float4 lo = *(const float4*)ap;
                float4 hi = *(const float4*)(ap + 4);
                frag_ab t;
                t[0] = f2bf(lo.x); t[1] = f2bf(lo.y); t[2] = f2bf(lo.z); t[3] = f2bf(lo.w);
                t[4] = f2bf(hi.x); t[5] = f2bf(hi.y); t[6] = f2bf(hi.z); t[7] = f2bf(hi.w);
                af[mi] = t;
            }
        }
        frag_ab bf[NI];
#pragma unroll
        for (int ni = 0; ni < NI; ++ni)
            bf[ni] = *(const frag_ab*)(Bt + (size_t)(bn + ni * 16 + r15) * K + kb);
#pragma unroll
        for (int mi = 0; mi < 4; ++mi)
#pragma unroll
            for (int ni = 0; ni < NI; ++ni)
                acc[mi][ni] = __builtin_amdgcn_mfma_f32_16x16x32_bf16(af[mi], bf[ni],
                                                                      acc[mi][ni], 0, 0, 0);
    }

#pragma unroll
    for (int mi = 0; mi < 4; ++mi) {
#pragma unroll
        for (int j = 0; j < 4; ++j) {
            const int row = bm + mi * 16 + g * 4 + j;
            if (row >= M) continue;
            const float s = SCALE ? dinv[row] : 1.0f;
#pragma unroll
            for (int ni = 0; ni < NI; ++ni) {
                const int col = bn + ni * 16 + r15;
                float v = acc[mi][ni][j] * s;
                if (BIAS) v += bias[col];
                if constexpr (OUT_BF16)
                    ((short*)Cv)[(size_t)row * N + col] = f2bf(v);
                else
                    ((float*)Cv)[(size_t)row * N + col] = v;
            }
        }
    }
}

// ------------------------------ aggregation --------------------------------
// out[d] = relu(dinv[d]*(sum_{s in CSR[d]} hs[s] + hs[d]) + b). bf16 in/out,
// fp32 accum, self term last. One wave per node, V bf16 per lane.
template<int V>
__device__ __forceinline__ void vloadbf(float (&d)[V], const u16* __restrict__ p) {
    if constexpr (V == 4) {
        uint2 u = *(const uint2*)p;
        d[0] = __builtin_bit_cast(float, u.x << 16);
        d[1] = __builtin_bit_cast(float, u.x & 0xffff0000u);
        d[2] = __builtin_bit_cast(float, u.y << 16);
        d[3] = __builtin_bit_cast(float, u.y & 0xffff0000u);
    } else {
        unsigned u = *(const unsigned*)p;
        d[0] = __builtin_bit_cast(float, u << 16);
        d[1] = __builtin_bit_cast(float, u & 0xffff0000u);
    }
}

template<int V>
__global__ __launch_bounds__(256) void agg_kernel(const u16* __restrict__ hs,
                                                  const int* __restrict__ csr,
                                                  const int* __restrict__ offs,
                                                  const float* __restrict__ dinv,
                                                  const float* __restrict__ bias,
                                                  u16* __restrict__ out,
                                                  int n, int F) {
    const int node = blockIdx.x * 4 + (threadIdx.x >> 6);
    if (node >= n) return;
    const int lane = threadIdx.x & 63;
    const int c0 = lane * V;

    float self[V];
    vloadbf<V>(self, hs + (size_t)node * F + c0);

    float acc[V];
#pragma unroll
    for (int j = 0; j < V; ++j) acc[j] = 0.f;

    int e = offs[node];
    const int end = offs[node + 1];
    for (; e + 4 <= end; e += 4) {
        int s0 = csr[e], s1 = csr[e + 1], s2 = csr[e + 2], s3 = csr[e + 3];
        float t0[V], t1[V], t2[V], t3[V];
        vloadbf<V>(t0, hs + (size_t)s0 * F + c0);
        vloadbf<V>(t1, hs + (size_t)s1 * F + c0);
        vloadbf<V>(t2, hs + (size_t)s2 * F + c0);
        vloadbf<V>(t3, hs + (size_t)s3 * F + c0);
#pragma unroll
        for (int j = 0; j < V; ++j) acc[j] += ((t0[j] + t1[j]) + (t2[j] + t3[j]));
    }
    for (; e < end; ++e) {
        float tv[V];
        vloadbf<V>(tv, hs + (size_t)csr[e] * F + c0);
#pragma unroll
        for (int j = 0; j < V; ++j) acc[j] += tv[j];
    }

    const float di = dinv[node];
    u16 res[V];
#pragma unroll
    for (int j = 0; j < V; ++j) {
        float v = fmaf(acc[j] + self[j], di, bias[c0 + j]);
        res[j] = (u16)f2bf(fmaxf(v, 0.f));
    }
    if constexpr (V == 4) {
        uint2 o;
        o.x = (unsigned)res[0] | ((unsigned)res[1] << 16);
        o.y = (unsigned)res[2] | ((unsigned)res[3] << 16);
        *(uint2*)(out + (size_t)node * F + c0) = o;
    } else {
        unsigned o = (unsigned)res[0] | ((unsigned)res[1] << 16);
        *(unsigned*)(out + (size_t)node * F + c0) = o;
    }
}

// ---------------------------------------------------------------------------

extern "C" void kernel_launch(void* const* d_in, const int* in_sizes, int n_in,
                              void* d_out, int out_size, void* d_ws, size_t ws_size,
                              hipStream_t stream) {
    const float* x  = (const float*)d_in[0];
    const int*   ei = (const int*)d_in[1];
    const float* W1 = (const float*)d_in[2];
    const float* b1 = (const float*)d_in[3];
    const float* W2 = (const float*)d_in[4];
    const float* b2 = (const float*)d_in[5];
    const float* Wl = (const float*)d_in[6];
    const float* bl = (const float*)d_in[7];

    const int E = in_sizes[1] / 2;    // 1,600,000
    const int n = in_sizes[0] / 256;  // 50,000
    const int* src = ei;
    const int* dst = ei + E;
    const int CH = (E + NB - 1) / NB;

    char* ws = (char*)d_ws;
    size_t off = 0;
    auto alloc = [&](size_t bytes) -> void* {
        void* p = ws + off;
        off += (bytes + 255) & ~(size_t)255;
        return p;
    };
    short* h      = (short*)alloc((size_t)n * 256 * 2);   // bf16 h1 / h2
    short* a      = (short*)alloc((size_t)n * 256 * 2);   // bf16 a1 / a2
    int*   counts = (int*)alloc((size_t)n * 4);
    int*   offs   = (int*)alloc((size_t)(n + 1) * 4);
    float* dinv   = (float*)alloc((size_t)n * 4);
    int*   csr    = (int*)alloc((size_t)E * 4);
    int*   h1     = (int*)alloc((size_t)NB * 256 * 4);
    int*   h2     = (int*)alloc((size_t)NB * 256 * 4);
    int*   tot1   = (int*)alloc(256 * 4);
    int*   tot2   = (int*)alloc(256 * 4);
    int*   db1    = (int*)alloc(256 * 4);
    int*   db2    = (int*)alloc(256 * 4);
    short* wt1    = (short*)alloc((size_t)256 * 256 * 2);
    short* wt2    = (short*)alloc((size_t)128 * 256 * 2);
    short* wtl    = (short*)alloc((size_t)64 * 128 * 2);
    // rec1 (12.8 MB) aliases 'a' (25.6 MB): CSR build completes before 'a' is used.
    uint2* rec1   = (uint2*)a;
    (void)ws_size;

    hipMemsetAsync(counts, 0, (size_t)n * 4, stream);
    prep_w<<<(256 * 256 + 255) / 256, 256, 0, stream>>>(W1, wt1, 256, 256);
    prep_w<<<(256 * 128 + 255) / 256, 256, 0, stream>>>(W2, wt2, 256, 128);
    prep_w<<<(128 * 64 + 255) / 256, 256, 0, stream>>>(Wl, wtl, 128, 64);

    count_kernel<<<1024, 256, 0, stream>>>(dst, E, counts);
    dinv_kernel<<<(n + 255) / 256, 256, 0, stream>>>(counts, dinv, n);
    scan_kernel<<<1, 1024, 0, stream>>>(counts, offs, n, E);

    // Stable radix sort by dst: pass 1 (low byte) then pass 2 (high byte).
    hist_kernel<1><<<NB, 256, 0, stream>>>(dst, E, CH, h1);
    row_scan_kernel<<<256, 256, 0, stream>>>(h1, tot1);
    digit_scan_kernel<<<1, 256, 0, stream>>>(tot1, db1);
    scatter_kernel<1><<<NB, 64, 0, stream>>>(dst, src, E, CH, h1, db1, rec1);
    hist_kernel<2><<<NB, 256, 0, stream>>>(rec1, E, CH, h2);
    row_scan_kernel<<<256, 256, 0, stream>>>(h2, tot2);
    digit_scan_kernel<<<1, 256, 0, stream>>>(tot2, db2);
    scatter_kernel<2><<<NB, 64, 0, stream>>>(rec1, nullptr, E, CH, h2, db2, csr);

    // Layer 1: h = (x @ W1) * dinv[row]  [bf16]; a = relu(agg(h) + b1) [bf16]
    gemm_mfma<2, 2, 4, false, true, false, true>
        <<<dim3(2, (n + 127) / 128), 256, 0, stream>>>(x, wt1, dinv, nullptr, h, n, 256, 256);
    agg_kernel<4><<<(n + 3) / 4, 256, 0, stream>>>((const u16*)h, csr, offs, dinv, b1,
                                                   (u16*)a, n, 256);

    // Layer 2: h = (a @ W2) * dinv[row] [bf16]; a = relu(agg(h) + b2) [bf16]
    gemm_mfma<1, 4, 2, true, true, false, true>
        <<<dim3(1, (n + 63) / 64), 256, 0, stream>>>(a, wt2, dinv, nullptr, h, n, 128, 256);
    agg_kernel<2><<<(n + 3) / 4, 256, 0, stream>>>((const u16*)h, csr, offs, dinv, b2,
                                                   (u16*)a, n, 128);

    // Head: out = a @ Wl + bl  [fp32]
    gemm_mfma<1, 4, 1, true, false, true, false>
        <<<dim3(1, (n + 63) / 64), 256, 0, stream>>>(a, wtl, nullptr, bl, d_out, n, 64, 128);
}